// Round 9
// baseline (563.767 us; speedup 1.0000x reference)
//
#include <hip/hip_runtime.h>

#define B_ 2048
#define T_ 200
#define D_ 64

typedef _Float16 half_t;
typedef __attribute__((ext_vector_type(8))) _Float16 h8;
typedef __attribute__((ext_vector_type(4))) float f32x4;

// D = A(16x32) * B(32x16) + C, fp16 in / fp32 acc.
// A: lane l holds A[row=l&15][k=(l>>4)*8 + j], j=0..7
// B: lane l holds B[k=(l>>4)*8 + j][col=l&15]
// C/D: lane l holds D[row=(l>>4)*4 + reg][col=l&15], reg=0..3  [HW-verified layout]
__device__ __forceinline__ f32x4 MF(h8 a, h8 b, f32x4 c) {
  return __builtin_amdgcn_mfma_f32_16x16x32_f16(a, b, c, 0, 0, 0);
}

__device__ __forceinline__ float sigmoidf_(float x) {
  return 1.0f / (1.0f + __expf(-x));
}
__device__ __forceinline__ float tanhf_(float x) {
  x = fminf(fmaxf(x, -15.0f), 15.0f);
  float e = __expf(2.0f * x);
  return (e - 1.0f) / (e + 1.0f);
}

// One wave per block; 16 batch rows per wave. Weights live in LDS as
// pre-swizzled MFMA B-fragments (no register residency required -> sidesteps
// the remat/spill pathology of rounds 2-8). h/rh cross D->A layout via a
// 4KB LDS bounce. Single kernel: x is consumed directly (no XP workspace).
__global__ __launch_bounds__(64) void augru_mfma(
    const float* __restrict__ X, const int* __restrict__ SL,
    const float* __restrict__ ATT, const float* __restrict__ Wg,
    const float* __restrict__ bg, const float* __restrict__ Wc,
    const float* __restrict__ bc, float* __restrict__ OUT) {
  __shared__ h8 sBG[4][8][64];                    // gate B-frags [ks][nt][lane] 32KB
  __shared__ h8 sBC[4][4][64];                    // cand B-frags 16KB
  __shared__ __align__(16) half_t sAh[2][2][512]; // A staging: [h|rh][ks-local][la*8+j] 4KB

  const int l = threadIdx.x;
  const int b0 = blockIdx.x * 16;
  const int rA = l & 15;        // A-operand row / D-operand col (both = l&15)
  const int kq = l >> 4;        // k-quarter for A/B, row-quarter for D
  const int rowD = kq * 4;      // D rows rowD..rowD+3 (reg 0..3)
  // A-layout staging address for element (row=rowD+reg, col c=rA+16*tt):
  //   la = row + 16*((c&31)>>3), j = c&7  ->  idx = basel + reg*8 + (tt&1)*256
  const int basel = (rowD + 16 * ((rA >> 3) & 1)) * 8 + (l & 7);

  // ---- stage weights as B-fragments (one-time) ----
  for (int ks = 0; ks < 4; ++ks)
    for (int nt = 0; nt < 8; ++nt) {
      h8 v;
#pragma unroll
      for (int j = 0; j < 8; ++j)
        v[j] = (half_t)Wg[(ks * 32 + kq * 8 + j) * 128 + nt * 16 + rA];
      sBG[ks][nt][l] = v;
    }
  for (int ks = 0; ks < 4; ++ks)
    for (int nt = 0; nt < 4; ++nt) {
      h8 v;
#pragma unroll
      for (int j = 0; j < 8; ++j)
        v[j] = (half_t)Wc[(ks * 32 + kq * 8 + j) * 64 + nt * 16 + rA];
      sBC[ks][nt][l] = v;
    }
  {
    h8 z;
#pragma unroll
    for (int j = 0; j < 8; ++j) z[j] = (half_t)0.f;
    ((h8*)&sAh[0][0][0])[l] = z;  // h0 = 0
    ((h8*)&sAh[0][1][0])[l] = z;
  }
  __syncthreads();

  // biases in D-layout (col = rA + 16*nt)
  const float bgv0 = bg[rA], bgv1 = bg[rA + 16], bgv2 = bg[rA + 32],
              bgv3 = bg[rA + 48], bgv4 = bg[rA + 64], bgv5 = bg[rA + 80],
              bgv6 = bg[rA + 96], bgv7 = bg[rA + 112];
  const float bcv0 = bc[rA], bcv1 = bc[rA + 16], bcv2 = bc[rA + 32],
              bcv3 = bc[rA + 48];

  const int L0 = SL[b0 + rowD + 0];
  const int L1 = SL[b0 + rowD + 1];
  const int L2 = SL[b0 + rowD + 2];
  const int L3 = SL[b0 + rowD + 3];
  int Lm = 1;
  for (int r = 0; r < 16; ++r) {
    const int v = SL[b0 + r];
    Lm = v > Lm ? v : Lm;
  }

  const float* __restrict__ xbase = X + (size_t)(b0 + rA) * (T_ * D_) + kq * 8;
  const float* __restrict__ ap = ATT + (size_t)(b0 + rowD) * T_;
  float* __restrict__ obase = OUT + (size_t)b0 * (T_ * D_);

  // x prefetch (t=0): ks0 = k 0..31, ks1 = k 32..63 for this lane's slice
  f32x4 xA0 = *(const f32x4*)(xbase);
  f32x4 xA1 = *(const f32x4*)(xbase + 4);
  f32x4 xB0 = *(const f32x4*)(xbase + 32);
  f32x4 xB1 = *(const f32x4*)(xbase + 36);
  float at0 = ap[0], at1 = ap[T_], at2 = ap[2 * T_], at3 = ap[3 * T_];

  f32x4 hD0 = {0.f, 0.f, 0.f, 0.f}, hD1 = {0.f, 0.f, 0.f, 0.f},
        hD2 = {0.f, 0.f, 0.f, 0.f}, hD3 = {0.f, 0.f, 0.f, 0.f};

  for (int t = 0; t < Lm; ++t) {
    // x -> fp16 A-fragments
    h8 ax0, ax1;
#pragma unroll
    for (int j = 0; j < 4; ++j) {
      ax0[j] = (half_t)xA0[j];
      ax0[4 + j] = (half_t)xA1[j];
      ax1[j] = (half_t)xB0[j];
      ax1[4 + j] = (half_t)xB1[j];
    }

    // prefetch t+1 (clamped) under the compute
    const int tn = (t + 1 < Lm) ? t + 1 : t;
    const f32x4 nA0 = *(const f32x4*)(xbase + tn * 64);
    const f32x4 nA1 = *(const f32x4*)(xbase + tn * 64 + 4);
    const f32x4 nB0 = *(const f32x4*)(xbase + tn * 64 + 32);
    const f32x4 nB1 = *(const f32x4*)(xbase + tn * 64 + 36);
    const float na0 = ap[tn], na1 = ap[T_ + tn], na2 = ap[2 * T_ + tn],
                na3 = ap[3 * T_ + tn];

    // h A-fragments (written at end of previous step; same-wave DS in-order)
    const h8 ah0 = ((const h8*)&sAh[0][0][0])[l];
    const h8 ah1 = ((const h8*)&sAh[0][1][0])[l];

    // ---- gates: [x|h](16x128) @ Wg(128x128) ----
    f32x4 g0 = {bgv0, bgv0, bgv0, bgv0}, g1 = {bgv1, bgv1, bgv1, bgv1},
          g2 = {bgv2, bgv2, bgv2, bgv2}, g3 = {bgv3, bgv3, bgv3, bgv3},
          g4 = {bgv4, bgv4, bgv4, bgv4}, g5 = {bgv5, bgv5, bgv5, bgv5},
          g6 = {bgv6, bgv6, bgv6, bgv6}, g7 = {bgv7, bgv7, bgv7, bgv7};
#define GNT(nt)                              \
  g##nt = MF(ax0, sBG[0][nt][l], g##nt);     \
  g##nt = MF(ax1, sBG[1][nt][l], g##nt);     \
  g##nt = MF(ah0, sBG[2][nt][l], g##nt);     \
  g##nt = MF(ah1, sBG[3][nt][l], g##nt);
    GNT(0) GNT(1) GNT(2) GNT(3) GNT(4) GNT(5) GNT(6) GNT(7)
#undef GNT

    // r = sigmoid(g0..3); stage rh = r*h into A-layout
#define RH(tt, reg)                                               \
  sAh[1][(tt) >> 1][basel + (reg)*8 + ((tt)&1) * 256] =           \
      (half_t)(sigmoidf_(g##tt[reg]) * hD##tt[reg]);
    RH(0, 0) RH(0, 1) RH(0, 2) RH(0, 3)
    RH(1, 0) RH(1, 1) RH(1, 2) RH(1, 3)
    RH(2, 0) RH(2, 1) RH(2, 2) RH(2, 3)
    RH(3, 0) RH(3, 1) RH(3, 2) RH(3, 3)
#undef RH
    asm volatile("" ::: "memory");

    const h8 ar0 = ((const h8*)&sAh[1][0][0])[l];
    const h8 ar1 = ((const h8*)&sAh[1][1][0])[l];

    // ---- candidate: [x|rh](16x128) @ Wc(128x64) ----
    f32x4 c0 = {bcv0, bcv0, bcv0, bcv0}, c1 = {bcv1, bcv1, bcv1, bcv1},
          c2 = {bcv2, bcv2, bcv2, bcv2}, c3 = {bcv3, bcv3, bcv3, bcv3};
#define CNT(nt)                              \
  c##nt = MF(ax0, sBC[0][nt][l], c##nt);     \
  c##nt = MF(ax1, sBC[1][nt][l], c##nt);     \
  c##nt = MF(ar0, sBC[2][nt][l], c##nt);     \
  c##nt = MF(ar1, sBC[3][nt][l], c##nt);
    CNT(0) CNT(1) CNT(2) CNT(3)
#undef CNT

    // ---- blend, mask, store, stage h for next step ----
#define FIN(tt, GU, reg)                                                      \
  {                                                                           \
    const float uv = sigmoidf_(GU[reg]);                                      \
    const float cv = tanhf_(c##tt[reg]);                                      \
    const float hp = hD##tt[reg];                                             \
    const float hn0 = fmaf(at##reg * uv, cv - hp, hp);                        \
    const bool ok = t < L##reg;                                               \
    const float hn = ok ? hn0 : hp;                                           \
    hD##tt[reg] = hn;                                                         \
    obase[(size_t)(rowD + (reg)) * (T_ * D_) + t * 64 + rA + 16 * (tt)] =     \
        ok ? hn : 0.0f;                                                       \
    sAh[0][(tt) >> 1][basel + (reg)*8 + ((tt)&1) * 256] = (half_t)hn;         \
  }
    FIN(0, g4, 0) FIN(0, g4, 1) FIN(0, g4, 2) FIN(0, g4, 3)
    FIN(1, g5, 0) FIN(1, g5, 1) FIN(1, g5, 2) FIN(1, g5, 3)
    FIN(2, g6, 0) FIN(2, g6, 1) FIN(2, g6, 2) FIN(2, g6, 3)
    FIN(3, g7, 0) FIN(3, g7, 1) FIN(3, g7, 2) FIN(3, g7, 3)
#undef FIN
    asm volatile("" ::: "memory");

    xA0 = nA0; xA1 = nA1; xB0 = nB0; xB1 = nB1;
    at0 = na0; at1 = na1; at2 = na2; at3 = na3;
  }

  // zero-fill past the block's max length
  for (int t = Lm; t < T_; ++t) {
#define STZ(tt, reg)                                                          \
  obase[(size_t)(rowD + (reg)) * (T_ * D_) + t * 64 + rA + 16 * (tt)] = 0.0f;
    STZ(0, 0) STZ(0, 1) STZ(0, 2) STZ(0, 3)
    STZ(1, 0) STZ(1, 1) STZ(1, 2) STZ(1, 3)
    STZ(2, 0) STZ(2, 1) STZ(2, 2) STZ(2, 3)
    STZ(3, 0) STZ(3, 1) STZ(3, 2) STZ(3, 3)
#undef STZ
  }
}

extern "C" void kernel_launch(void* const* d_in, const int* in_sizes, int n_in,
                              void* d_out, int out_size, void* d_ws, size_t ws_size,
                              hipStream_t stream) {
  (void)in_sizes; (void)n_in; (void)d_ws; (void)ws_size; (void)out_size;
  const float* X  = (const float*)d_in[0];
  const int*   SL = (const int*)d_in[1];
  const float* A  = (const float*)d_in[2];
  const float* Wg = (const float*)d_in[3];
  const float* bg = (const float*)d_in[4];
  const float* Wc = (const float*)d_in[5];
  const float* bc = (const float*)d_in[6];
  float* O = (float*)d_out;

  augru_mfma<<<B_ / 16, 64, 0, stream>>>(X, SL, A, Wg, bg, Wc, bc, O);
}